// Round 4
// baseline (110.006 us; speedup 1.0000x reference)
//
#include <hip/hip_runtime.h>
#include <stdint.h>

#define B_ 4
#define N_ 512
#define F_ 64
#define R_ 128
#define PPI 511          // pairs per i = N-1
#define TJ 128           // j's per block
#define VSTR 136         // fp16 row stride in LDS (128 + 8 pad; 272B = 17*16B)

typedef _Float16 f16x8 __attribute__((ext_vector_type(8)));
typedef _Float16 f16x2 __attribute__((ext_vector_type(2)));
typedef float f32x4 __attribute__((ext_vector_type(4)));

__device__ __forceinline__ uint16_t f16bits(float x) {
  return __builtin_bit_cast(uint16_t, (_Float16)x);
}
__device__ __forceinline__ f16x2 cvt_pk(float a, float b) {
  return __builtin_bit_cast(f16x2, __builtin_amdgcn_cvt_pkrtz(a, b));
}

// ---------------- fused prep ----------------
// blocks [0,256): U'[b,i,r] = feat_i @ W1[:F] + b1 ; V[b,j,r] = feat_j @ W1[F:]
// blocks [256,320): pack W2^T into fp16 A-fragment order:
//   dst[((t*4+c)*64+lane)*8+jj] = W2[(32c+(lane>>4)*8+jj)*R + 16t+(lane&15)]
__global__ __launch_bounds__(256) void prep_all(
    const float* __restrict__ feat, const float* __restrict__ W1,
    const float* __restrict__ b1, const float* __restrict__ W2,
    uint16_t* __restrict__ U, uint16_t* __restrict__ V, uint16_t* __restrict__ w2f) {
  if (blockIdx.x >= 256) {
    const int d = (blockIdx.x - 256) * 256 + threadIdx.x;  // 0..16383
    const int jj = d & 7, lane = (d >> 3) & 63, tc = d >> 9;
    const int c = tc & 3, t = tc >> 2;
    const int rr = 32 * c + (lane >> 4) * 8 + jj;
    const int s = 16 * t + (lane & 15);
    w2f[d] = f16bits(W2[rr * R_ + s]);
    return;
  }
  __shared__ float fs[8][F_];
  const int row0 = blockIdx.x * 8;  // global row = b*N_ + i
  const int tid = threadIdx.x;
  for (int l = tid; l < 8 * F_; l += 256) fs[l >> 6][l & 63] = feat[row0 * F_ + l];
  __syncthreads();
  const int r = tid & 127, rh = tid >> 7;  // rh -> rows 4rh..4rh+3
  float aU[4], aV[4];
  const float bias = b1[r];
#pragma unroll
  for (int ii = 0; ii < 4; ++ii) { aU[ii] = bias; aV[ii] = 0.f; }
#pragma unroll 4
  for (int f = 0; f < F_; ++f) {
    const float wa = W1[f * R_ + r];
    const float wb = W1[(F_ + f) * R_ + r];
#pragma unroll
    for (int ii = 0; ii < 4; ++ii) {
      aU[ii] = fmaf(fs[rh * 4 + ii][f], wa, aU[ii]);
      aV[ii] = fmaf(fs[rh * 4 + ii][f], wb, aV[ii]);
    }
  }
#pragma unroll
  for (int ii = 0; ii < 4; ++ii) {
    const int row = row0 + rh * 4 + ii;
    U[row * R_ + r] = f16bits(aU[ii]);
    V[row * R_ + r] = f16bits(aV[ii]);
  }
}

// ---------------- Main fused kernel ----------------
// grid: B_ * (N_/2) * (N_/TJ) = 4096 blocks of 256 threads (4 waves).
// Block = (b, i0..i0+1, j0..j0+127). Wave w: il = w>>1 (i = i0+il), th = w&1
// (t-half: t = th*4 + t', s-range [64*th, 64*th+64)). Each wave holds half of
// W2^T in regs (64 VGPRs) -> ~150 live regs -> 3 waves/SIMD.
__global__ __launch_bounds__(256, 3) void relnet_main(
    const uint16_t* __restrict__ U, const uint16_t* __restrict__ V,
    const uint16_t* __restrict__ w2f, const float* __restrict__ b2,
    const float* __restrict__ W3, const float* __restrict__ b3,
    float* __restrict__ out) {
  __shared__ __align__(16) uint16_t Vs[TJ * VSTR];
  __shared__ float pl[4][2][2][8][16];  // [quad][th][il][jt][l4]

  const int bid = blockIdx.x;
  const int jb = bid & 3, ib = (bid >> 2) & 255, b = bid >> 10;
  const int i0 = ib * 2, j0 = jb * TJ;
  const int tid = threadIdx.x;

  // stage V rows j0..j0+127 (fp16, padded stride; 8 uint4 per thread)
  {
    const uint4* sv = (const uint4*)(V + (b * N_ + j0) * R_);
    for (int l = tid; l < TJ * 16; l += 256) {
      const int row = l >> 4, seg = l & 15;
      *(uint4*)&Vs[row * VSTR + seg * 8] = sv[row * 16 + seg];
    }
  }

  const int lane = tid & 63, wave = tid >> 6;
  const int quad = lane >> 4, l4 = lane & 15;
  const int il = wave >> 1, th = wave & 1;
  const int i = i0 + il;

  // this wave's half of W2^T A-frags (t = th*4 + t'): 16 frags = 64 regs
  f16x8 w2r[4][4];
#pragma unroll
  for (int tp = 0; tp < 4; ++tp)
#pragma unroll
    for (int c = 0; c < 4; ++c) {
      const int t = th * 4 + tp;
      const uint4 w = *(const uint4*)(w2f + ((size_t)((t * 4 + c) * 64 + lane)) * 8);
      w2r[tp][c] = __builtin_bit_cast(f16x8, w);
    }

  // epilogue constants for this t-half: s = 16t + 4*quad + 2h + {0,1}
  f16x2 b2p[4][2], w3p[4][2];
#pragma unroll
  for (int tp = 0; tp < 4; ++tp)
#pragma unroll
    for (int h = 0; h < 2; ++h) {
      const int s0 = 16 * (th * 4 + tp) + 4 * quad + 2 * h;
      b2p[tp][h] = (f16x2){(_Float16)b2[s0], (_Float16)b2[s0 + 1]};
      w3p[tp][h] = (f16x2){(_Float16)W3[s0], (_Float16)W3[s0 + 1]};
    }

  // u' frag for this wave's i, straight from global (loop-invariant)
  f16x8 uf[4];
#pragma unroll
  for (int c = 0; c < 4; ++c)
    uf[c] = __builtin_bit_cast(f16x8,
        *(const uint4*)(U + (size_t)(b * N_ + i) * R_ + c * 32 + quad * 8));

  const f16x8 z8 = {};
  const f16x2 z2 = {};

  __syncthreads();

  float part[8];

#pragma unroll 2
  for (int jt = 0; jt < 8; ++jt) {
    // h1 B-frags: B[k = 32c + quad*8 + jj][n = l4] = relu(u'[k] + v_j[k])
    f16x8 hb[4];
#pragma unroll
    for (int c = 0; c < 4; ++c) {
      const uint4 v = *(const uint4*)&Vs[(jt * 16 + l4) * VSTR + c * 32 + quad * 8];
      hb[c] = __builtin_elementwise_max(__builtin_bit_cast(f16x8, v) + uf[c], z8);
    }

    f32x4 acc[4];
#pragma unroll
    for (int tp = 0; tp < 4; ++tp) acc[tp] = (f32x4){0.f, 0.f, 0.f, 0.f};
#pragma unroll
    for (int c = 0; c < 4; ++c)
#pragma unroll
      for (int tp = 0; tp < 4; ++tp)
        acc[tp] = __builtin_amdgcn_mfma_f32_16x16x32_f16(w2r[tp][c], hb[c], acc[tp], 0, 0, 0);

    // in-lane layer-3 partial only (cross-lane deferred out of the loop)
    float t0 = 0.f, t1 = 0.f, t2 = 0.f, t3 = 0.f;
#pragma unroll
    for (int tp = 0; tp < 4; tp += 2) {
      f16x2 p0 = cvt_pk(acc[tp][0], acc[tp][1]);
      f16x2 p1 = cvt_pk(acc[tp][2], acc[tp][3]);
      p0 = __builtin_elementwise_max(p0 + b2p[tp][0], z2);
      p1 = __builtin_elementwise_max(p1 + b2p[tp][1], z2);
      t0 = __builtin_amdgcn_fdot2(p0, w3p[tp][0], t0, false);
      t1 = __builtin_amdgcn_fdot2(p1, w3p[tp][1], t1, false);
      f16x2 q0 = cvt_pk(acc[tp + 1][0], acc[tp + 1][1]);
      f16x2 q1 = cvt_pk(acc[tp + 1][2], acc[tp + 1][3]);
      q0 = __builtin_elementwise_max(q0 + b2p[tp + 1][0], z2);
      q1 = __builtin_elementwise_max(q1 + b2p[tp + 1][1], z2);
      t2 = __builtin_amdgcn_fdot2(q0, w3p[tp + 1][0], t2, false);
      t3 = __builtin_amdgcn_fdot2(q1, w3p[tp + 1][1], t3, false);
    }
    part[jt] = (t0 + t1) + (t2 + t3);
  }

  // dump per-lane partials (all jt at once), one barrier, then clean reduce
#pragma unroll
  for (int jt = 0; jt < 8; ++jt) pl[quad][th][il][jt][l4] = part[jt];

  __syncthreads();

  {
    const int ril = tid >> 7, rjt = (tid >> 4) & 7, rl4 = tid & 15;
    float sum = b3[0];
#pragma unroll
    for (int q = 0; q < 4; ++q)
#pragma unroll
      for (int h = 0; h < 2; ++h) sum += pl[q][h][ril][rjt][rl4];
    const int ri = i0 + ril;
    const int j = j0 + rjt * 16 + rl4;
    if (j != ri) {
      const int p = (b * N_ + ri) * PPI + (j < ri ? j : j - 1);
      out[p] = sum;
    }
  }
}

extern "C" void kernel_launch(void* const* d_in, const int* in_sizes, int n_in,
                              void* d_out, int out_size, void* d_ws, size_t ws_size,
                              hipStream_t stream) {
  const float* feat = (const float*)d_in[0];
  const float* W1 = (const float*)d_in[1];
  const float* b1 = (const float*)d_in[2];
  const float* W2 = (const float*)d_in[3];
  const float* b2 = (const float*)d_in[4];
  const float* W3 = (const float*)d_in[5];
  const float* b3 = (const float*)d_in[6];

  uint16_t* U = (uint16_t*)d_ws;                 // B*N*R fp16 = 512 KiB
  uint16_t* V = U + (size_t)B_ * N_ * R_;        // 512 KiB
  uint16_t* w2f = V + (size_t)B_ * N_ * R_;      // 32 KiB

  prep_all<<<256 + 64, 256, 0, stream>>>(feat, W1, b1, W2, U, V, w2f);
  relnet_main<<<B_ * (N_ / 2) * (N_ / TJ), 256, 0, stream>>>(U, V, w2f, b2, W3, b3,
                                                             (float*)d_out);
}

// Round 5
// 103.914 us; speedup vs baseline: 1.0586x; 1.0586x over previous
//
#include <hip/hip_runtime.h>
#include <stdint.h>

#define B_ 4
#define N_ 512
#define F_ 64
#define R_ 128
#define PPI 511          // pairs per i = N-1
#define TJ 128           // j's per block
#define VSTR 136         // fp16 row stride in LDS (128 + 8 pad; 272B = 17*16B)

typedef _Float16 f16x8 __attribute__((ext_vector_type(8)));
typedef _Float16 f16x2 __attribute__((ext_vector_type(2)));
typedef float f32x4 __attribute__((ext_vector_type(4)));

__device__ __forceinline__ uint16_t f16bits(float x) {
  return __builtin_bit_cast(uint16_t, (_Float16)x);
}
__device__ __forceinline__ f16x2 cvt_pk(float a, float b) {
  return __builtin_bit_cast(f16x2, __builtin_amdgcn_cvt_pkrtz(a, b));
}

// ---------------- fused prep ----------------
// blocks [0,512): U'[b,i,r] = feat_i @ W1[:F] + b1 ; V[b,j,r] = feat_j @ W1[F:]
//   4 rows per block, 256 threads (tid>>7 picks row pair, tid&127 = r).
// blocks [512,576): pack W2^T into fp16 A-fragment order:
//   dst[((t*4+c)*64+lane)*8+jj] = W2[(32c+(lane>>4)*8+jj)*R + 16t+(lane&15)]
__global__ __launch_bounds__(256) void prep_all(
    const float* __restrict__ feat, const float* __restrict__ W1,
    const float* __restrict__ b1, const float* __restrict__ W2,
    uint16_t* __restrict__ U, uint16_t* __restrict__ V, uint16_t* __restrict__ w2f) {
  if (blockIdx.x >= 512) {
    const int d = (blockIdx.x - 512) * 256 + threadIdx.x;  // 0..16383
    const int jj = d & 7, lane = (d >> 3) & 63, tc = d >> 9;
    const int c = tc & 3, t = tc >> 2;
    const int rr = 32 * c + (lane >> 4) * 8 + jj;
    const int s = 16 * t + (lane & 15);
    w2f[d] = f16bits(W2[rr * R_ + s]);
    return;
  }
  __shared__ float fs[4][F_];
  const int row0 = blockIdx.x * 4;  // global row = b*N_ + i
  const int tid = threadIdx.x;
  if (tid < 4 * F_) fs[tid >> 6][tid & 63] = feat[row0 * F_ + tid];
  __syncthreads();
  const int r = tid & 127, rh = tid >> 7;  // rh -> rows 2rh, 2rh+1
  float aU[2], aV[2];
  const float bias = b1[r];
#pragma unroll
  for (int ii = 0; ii < 2; ++ii) { aU[ii] = bias; aV[ii] = 0.f; }
#pragma unroll 8
  for (int f = 0; f < F_; ++f) {
    const float wa = W1[f * R_ + r];
    const float wb = W1[(F_ + f) * R_ + r];
#pragma unroll
    for (int ii = 0; ii < 2; ++ii) {
      aU[ii] = fmaf(fs[rh * 2 + ii][f], wa, aU[ii]);
      aV[ii] = fmaf(fs[rh * 2 + ii][f], wb, aV[ii]);
    }
  }
#pragma unroll
  for (int ii = 0; ii < 2; ++ii) {
    const int row = row0 + rh * 2 + ii;
    U[row * R_ + r] = f16bits(aU[ii]);
    V[row * R_ + r] = f16bits(aV[ii]);
  }
}

// ---------------- Main fused kernel ----------------
// grid: B_ * (N_/2) * (N_/TJ) = 4096 blocks of 256 threads (4 waves).
// Block = (b, i0..i0+1, j0..j0+127). Wave w: il = w>>1 (i = i0+il), th = w&1
// (t-half: t = th*4 + t'). Each wave holds half of W2^T in regs (64 VGPRs).
__global__ __launch_bounds__(256, 3) void relnet_main(
    const uint16_t* __restrict__ U, const uint16_t* __restrict__ V,
    const uint16_t* __restrict__ w2f, const float* __restrict__ b2,
    const float* __restrict__ W3, const float* __restrict__ b3,
    float* __restrict__ out) {
  __shared__ __align__(16) uint16_t Vs[TJ * VSTR];
  __shared__ float pl[4][2][2][8][16];  // [quad][th][il][jt][l4]

  const int bid = blockIdx.x;
  const int jb = bid & 3, ib = (bid >> 2) & 255, b = bid >> 10;
  const int i0 = ib * 2, j0 = jb * TJ;
  const int tid = threadIdx.x;

  // stage V rows j0..j0+127 (fp16, padded stride; 8 uint4 per thread)
  {
    const uint4* sv = (const uint4*)(V + (b * N_ + j0) * R_);
    for (int l = tid; l < TJ * 16; l += 256) {
      const int row = l >> 4, seg = l & 15;
      *(uint4*)&Vs[row * VSTR + seg * 8] = sv[row * 16 + seg];
    }
  }

  const int lane = tid & 63, wave = tid >> 6;
  const int quad = lane >> 4, l4 = lane & 15;
  const int il = wave >> 1, th = wave & 1;
  const int i = i0 + il;

  // this wave's half of W2^T A-frags (t = th*4 + t'): 16 frags = 64 regs
  f16x8 w2r[4][4];
#pragma unroll
  for (int tp = 0; tp < 4; ++tp)
#pragma unroll
    for (int c = 0; c < 4; ++c) {
      const int t = th * 4 + tp;
      const uint4 w = *(const uint4*)(w2f + ((size_t)((t * 4 + c) * 64 + lane)) * 8);
      w2r[tp][c] = __builtin_bit_cast(f16x8, w);
    }

  // epilogue constants for this t-half: s = 16t + 4*quad + reg
  // b2 folded into acc init (fp32 exact); W3 as packed fp16 for fdot2
  f32x4 b2f[4];
  f16x2 w3p[4][2];
#pragma unroll
  for (int tp = 0; tp < 4; ++tp) {
    const int s0 = 16 * (th * 4 + tp) + 4 * quad;
    b2f[tp] = (f32x4){b2[s0], b2[s0 + 1], b2[s0 + 2], b2[s0 + 3]};
    w3p[tp][0] = (f16x2){(_Float16)W3[s0], (_Float16)W3[s0 + 1]};
    w3p[tp][1] = (f16x2){(_Float16)W3[s0 + 2], (_Float16)W3[s0 + 3]};
  }

  // u' frag for this wave's i, straight from global (loop-invariant)
  f16x8 uf[4];
#pragma unroll
  for (int c = 0; c < 4; ++c)
    uf[c] = __builtin_bit_cast(f16x8,
        *(const uint4*)(U + (size_t)(b * N_ + i) * R_ + c * 32 + quad * 8));

  const f16x8 z8 = {};
  const f16x2 z2 = {};

  __syncthreads();

#pragma unroll
  for (int jt = 0; jt < 8; ++jt) {
    // h1 B-frags: B[k = 32c + quad*8 + jj][n = l4] = relu(u'[k] + v_j[k])
    f16x8 hb[4];
#pragma unroll
    for (int c = 0; c < 4; ++c) {
      const uint4 v = *(const uint4*)&Vs[(jt * 16 + l4) * VSTR + c * 32 + quad * 8];
      hb[c] = __builtin_elementwise_max(__builtin_bit_cast(f16x8, v) + uf[c], z8);
    }

    f32x4 acc[4];
#pragma unroll
    for (int tp = 0; tp < 4; ++tp) acc[tp] = b2f[tp];
#pragma unroll
    for (int c = 0; c < 4; ++c)
#pragma unroll
      for (int tp = 0; tp < 4; ++tp)
        acc[tp] = __builtin_amdgcn_mfma_f32_16x16x32_f16(w2r[tp][c], hb[c], acc[tp], 0, 0, 0);

    // layer3 in-lane partial: relu + fp16 dot (b2 already in acc)
    float t0 = 0.f, t1 = 0.f, t2 = 0.f, t3 = 0.f;
#pragma unroll
    for (int tp = 0; tp < 4; tp += 2) {
      f16x2 p0 = __builtin_elementwise_max(cvt_pk(acc[tp][0], acc[tp][1]), z2);
      f16x2 p1 = __builtin_elementwise_max(cvt_pk(acc[tp][2], acc[tp][3]), z2);
      t0 = __builtin_amdgcn_fdot2(p0, w3p[tp][0], t0, false);
      t1 = __builtin_amdgcn_fdot2(p1, w3p[tp][1], t1, false);
      f16x2 q0 = __builtin_elementwise_max(cvt_pk(acc[tp + 1][0], acc[tp + 1][1]), z2);
      f16x2 q1 = __builtin_elementwise_max(cvt_pk(acc[tp + 1][2], acc[tp + 1][3]), z2);
      t2 = __builtin_amdgcn_fdot2(q0, w3p[tp + 1][0], t2, false);
      t3 = __builtin_amdgcn_fdot2(q1, w3p[tp + 1][1], t3, false);
    }
    // constant-offset LDS store per jt (no part[] array -> no scratch)
    pl[quad][th][il][jt][l4] = (t0 + t1) + (t2 + t3);
  }

  __syncthreads();

  {
    const int ril = tid >> 7, rjt = (tid >> 4) & 7, rl4 = tid & 15;
    float sum = b3[0];
#pragma unroll
    for (int q = 0; q < 4; ++q)
#pragma unroll
      for (int h = 0; h < 2; ++h) sum += pl[q][h][ril][rjt][rl4];
    const int ri = i0 + ril;
    const int j = j0 + rjt * 16 + rl4;
    if (j != ri) {
      const int p = (b * N_ + ri) * PPI + (j < ri ? j : j - 1);
      out[p] = sum;
    }
  }
}

extern "C" void kernel_launch(void* const* d_in, const int* in_sizes, int n_in,
                              void* d_out, int out_size, void* d_ws, size_t ws_size,
                              hipStream_t stream) {
  const float* feat = (const float*)d_in[0];
  const float* W1 = (const float*)d_in[1];
  const float* b1 = (const float*)d_in[2];
  const float* W2 = (const float*)d_in[3];
  const float* b2 = (const float*)d_in[4];
  const float* W3 = (const float*)d_in[5];
  const float* b3 = (const float*)d_in[6];

  uint16_t* U = (uint16_t*)d_ws;                 // B*N*R fp16 = 512 KiB
  uint16_t* V = U + (size_t)B_ * N_ * R_;        // 512 KiB
  uint16_t* w2f = V + (size_t)B_ * N_ * R_;      // 32 KiB

  prep_all<<<512 + 64, 256, 0, stream>>>(feat, W1, b1, W2, U, V, w2f);
  relnet_main<<<B_ * (N_ / 2) * (N_ / TJ), 256, 0, stream>>>(U, V, w2f, b2, W3, b3,
                                                             (float*)d_out);
}